// Round 6
// baseline (194.742 us; speedup 1.0000x reference)
//
#include <hip/hip_runtime.h>
#include <math.h>

#define GG 2000   // num_graphs (reference constant)

typedef short bf16x8 __attribute__((ext_vector_type(8)));
typedef float f32x4  __attribute__((ext_vector_type(4)));

__device__ __forceinline__ unsigned short f2b(float f) {
    unsigned int u = __float_as_uint(f);
    u += 0x7FFFu + ((u >> 16) & 1u);          // round-to-nearest-even
    return (unsigned short)(u >> 16);
}

// seg[g] = first node index with batch[node] >= g, g in [0, GG]
__global__ void lbound_kernel(const int* __restrict__ batch, int* __restrict__ seg, int n) {
    int g = blockIdx.x * blockDim.x + threadIdx.x;
    if (g > GG) return;
    int lo = 0, hi = n;
    while (lo < hi) { int mid = (lo + hi) >> 1; if (batch[mid] < g) lo = mid + 1; else hi = mid; }
    seg[g] = lo;
}

// Wave-per-graph fused kernel. Block = 4 waves = 4 graphs; w1b staged once
// (read-only after one barrier). Everything else is wave-private: chunks of
// 16 nodes -> A-frags direct from global, GEMM1 (MFMA), tanh -> hb (4KB/wave),
// GEMM2, in-wave online softmax (shfl only), P -> pb (512B/wave), fp32 PV with
// coalesced L1-hot x reads. No __syncthreads in the main loop.
__global__ __launch_bounds__(256, 3) void fused_kernel(
    const float* __restrict__ x, const float* __restrict__ w1,
    const float* __restrict__ w2, const int* __restrict__ seg,
    float* __restrict__ out)
{
    __shared__ __align__(16) unsigned short w1b[16384]; // [128 hid][128 k] bf16, slot^=(row&7)
    __shared__ __align__(16) unsigned short hb[4][2048];// per-wave [16 m][128 hid] bf16, swizzled
    __shared__ __align__(16) float pb[4][128];          // per-wave P chunk [16 j][8 o]

    const int t = threadIdx.x;
    const int lane = t & 63;
    const int w = t >> 6;
    const int l15 = lane & 15;
    const int lg = lane >> 4;

    // ---- stage w1 -> bf16 LDS once per block ----
#pragma unroll
    for (int i = 0; i < 16; ++i) {
        int f4 = i * 256 + t;                  // 4096 float4
        int row = f4 >> 5, q = f4 & 31;
        float4 v = ((const float4*)w1)[f4];
        ushort4 p;
        p.x = f2b(v.x); p.y = f2b(v.y); p.z = f2b(v.z); p.w = f2b(v.w);
        int slot = (q >> 1) ^ (row & 7);
        *(ushort4*)((char*)w1b + row * 256 + slot * 16 + (q & 1) * 8) = p;
    }
    // ---- w2 b-frags in regs: lane -> col o=l15 (rows 8..15 zero) ----
    bf16x8 w2f[4];
    {
        const int o = l15;
#pragma unroll
        for (int ks = 0; ks < 4; ++ks) {
            float tmp[8];
            if (o < 8) {
                float4 u0 = ((const float4*)w2)[o * 32 + ks * 8 + lg * 2];
                float4 u1 = ((const float4*)w2)[o * 32 + ks * 8 + lg * 2 + 1];
                tmp[0]=u0.x; tmp[1]=u0.y; tmp[2]=u0.z; tmp[3]=u0.w;
                tmp[4]=u1.x; tmp[5]=u1.y; tmp[6]=u1.z; tmp[7]=u1.w;
            } else {
#pragma unroll
                for (int i = 0; i < 8; ++i) tmp[i] = 0.f;
            }
            bf16x8 r;
#pragma unroll
            for (int i = 0; i < 8; ++i) r[i] = (short)f2b(tmp[i]);
            w2f[ks] = r;
        }
    }
    __syncthreads();   // w1b staged; the ONLY block-wide barrier

    char*  myhb = (char*)hb + w * 4096;
    float* mypb = pb[w];

    const int g = blockIdx.x * 4 + w;          // grid=500 -> g in [0,2000)
    const int s = seg[g];
    const int e = seg[g + 1];

    float oa[8][2];                            // out accs: 8 heads x {f=lane, f=lane+64}
#pragma unroll
    for (int o = 0; o < 8; ++o) { oa[o][0] = 0.f; oa[o][1] = 0.f; }
    float mo = -INFINITY;                      // running max for o=l15 (junk if l15>=8)
    float ls = 0.f;                            // running denom for o=l15

    for (int nb = s; nb < e; nb += 16) {
        int arow = nb + l15; if (arow >= e) arow = e - 1;   // dup rows masked later
        // ---- GEMM1: 16 nodes x 128 hidden ----
        f32x4 acc1[8];
#pragma unroll
        for (int nt = 0; nt < 8; ++nt)
#pragma unroll
            for (int r = 0; r < 4; ++r) acc1[nt][r] = 0.f;
#pragma unroll
        for (int ks = 0; ks < 4; ++ks) {
            const float4* xp = (const float4*)x + (size_t)arow * 32 + ks * 8 + lg * 2;
            float4 u0 = xp[0], u1 = xp[1];
            float tmp[8] = {u0.x,u0.y,u0.z,u0.w,u1.x,u1.y,u1.z,u1.w};
            bf16x8 af;
#pragma unroll
            for (int i = 0; i < 8; ++i) af[i] = (short)f2b(tmp[i]);
#pragma unroll
            for (int nt = 0; nt < 8; ++nt) {
                int brow = nt * 16 + l15;
                int bslot = (ks * 4 + lg) ^ (brow & 7);
                bf16x8 bfr = *(bf16x8*)((char*)w1b + brow * 256 + bslot * 16);
                acc1[nt] = __builtin_amdgcn_mfma_f32_16x16x32_bf16(af, bfr, acc1[nt], 0, 0, 0);
            }
        }
        // ---- tanh -> myhb (wave-private; in-wave LDS ordering, no barrier) ----
#pragma unroll
        for (int nt = 0; nt < 8; ++nt)
#pragma unroll
            for (int r = 0; r < 4; ++r) {
                float aa = acc1[nt][r];
                float eo = __expf(-2.f * fabsf(aa));
                float th = copysignf((1.f - eo) * __builtin_amdgcn_rcpf(1.f + eo), aa);
                int m = lg * 4 + r;
                int n = nt * 16 + l15;
                int slot = (n >> 3) ^ (m & 7);
                *(unsigned short*)(myhb + m * 256 + slot * 16 + (n & 7) * 2) = f2b(th);
            }
        // ---- GEMM2: scores for 16 nodes x 8 heads (cols 8..15 padding) ----
        f32x4 acc2;
#pragma unroll
        for (int r = 0; r < 4; ++r) acc2[r] = 0.f;
#pragma unroll
        for (int ks = 0; ks < 4; ++ks) {
            int slot = (ks * 4 + lg) ^ (l15 & 7);
            bf16x8 hf = *(bf16x8*)(myhb + l15 * 256 + slot * 16);
            acc2 = __builtin_amdgcn_mfma_f32_16x16x32_bf16(hf, w2f[ks], acc2, 0, 0, 0);
        }
        // ---- in-wave online softmax (o = l15; rows rr = lg*4+r) ----
        float sreg[4];
#pragma unroll
        for (int r = 0; r < 4; ++r) {
            int rr = lg * 4 + r;
            sreg[r] = (l15 < 8 && (nb + rr) < e) ? acc2[r] : -INFINITY;
        }
        float pm = fmaxf(fmaxf(sreg[0], sreg[1]), fmaxf(sreg[2], sreg[3]));
        pm = fmaxf(pm, __shfl_xor(pm, 16));
        pm = fmaxf(pm, __shfl_xor(pm, 32));    // column max across the 4 k-groups
        float mn = fmaxf(mo, pm);
        float fac = __expf(mo - mn);           // lanes l15>=8: NaN, never consumed
        mo = mn;
        float psum = 0.f;
#pragma unroll
        for (int r = 0; r < 4; ++r) {
            float p = __expf(sreg[r] - mn);    // masked rows -> exp(-inf)=0
            psum += p;
            if (l15 < 8) mypb[(lg * 4 + r) * 8 + l15] = p;
        }
        psum += __shfl_xor(psum, 16);
        psum += __shfl_xor(psum, 32);
        ls = ls * fac + psum;
        // ---- rescale + PV (x rows L1-hot from A-frag pass) ----
        float fac8[8];
#pragma unroll
        for (int o = 0; o < 8; ++o) fac8[o] = __shfl(fac, o);
#pragma unroll
        for (int o = 0; o < 8; ++o) { oa[o][0] *= fac8[o]; oa[o][1] *= fac8[o]; }
#pragma unroll
        for (int j = 0; j < 16; ++j) {
            int node = nb + j; if (node >= e) node = e - 1;   // its p row is 0
            float xv0 = x[(size_t)node * 128 + lane];
            float xv1 = x[(size_t)node * 128 + 64 + lane];
            float4 p0 = ((const float4*)mypb)[j * 2];         // broadcast reads
            float4 p1 = ((const float4*)mypb)[j * 2 + 1];
            oa[0][0] = fmaf(p0.x, xv0, oa[0][0]); oa[0][1] = fmaf(p0.x, xv1, oa[0][1]);
            oa[1][0] = fmaf(p0.y, xv0, oa[1][0]); oa[1][1] = fmaf(p0.y, xv1, oa[1][1]);
            oa[2][0] = fmaf(p0.z, xv0, oa[2][0]); oa[2][1] = fmaf(p0.z, xv1, oa[2][1]);
            oa[3][0] = fmaf(p0.w, xv0, oa[3][0]); oa[3][1] = fmaf(p0.w, xv1, oa[3][1]);
            oa[4][0] = fmaf(p1.x, xv0, oa[4][0]); oa[4][1] = fmaf(p1.x, xv1, oa[4][1]);
            oa[5][0] = fmaf(p1.y, xv0, oa[5][0]); oa[5][1] = fmaf(p1.y, xv1, oa[5][1]);
            oa[6][0] = fmaf(p1.z, xv0, oa[6][0]); oa[6][1] = fmaf(p1.z, xv1, oa[6][1]);
            oa[7][0] = fmaf(p1.w, xv0, oa[7][0]); oa[7][1] = fmaf(p1.w, xv1, oa[7][1]);
        }
    }
    // ---- epilogue ----
    float ls8[8];
#pragma unroll
    for (int o = 0; o < 8; ++o) ls8[o] = __shfl(ls, o);
    float* og = out + (size_t)g * 1024;
    if (e > s) {
#pragma unroll
        for (int o = 0; o < 8; ++o) {
            og[o * 128 + lane]      = oa[o][0] / ls8[o];
            og[o * 128 + 64 + lane] = oa[o][1] / ls8[o];
        }
    } else {
#pragma unroll
        for (int o = 0; o < 8; ++o) {
            og[o * 128 + lane] = 0.f;
            og[o * 128 + 64 + lane] = 0.f;
        }
    }
}

extern "C" void kernel_launch(void* const* d_in, const int* in_sizes, int n_in,
                              void* d_out, int out_size, void* d_ws, size_t ws_size,
                              hipStream_t stream)
{
    const float* x     = (const float*)d_in[0];
    const int*   batch = (const int*)d_in[1];
    const float* w1    = (const float*)d_in[2];
    const float* w2    = (const float*)d_in[3];
    const int n_nodes  = in_sizes[1];
    float* out = (float*)d_out;

    int* seg = (int*)d_ws;   // GG+1 ints

    hipLaunchKernelGGL(lbound_kernel, dim3((GG + 256) / 256), dim3(256), 0, stream, batch, seg, n_nodes);
    hipLaunchKernelGGL(fused_kernel,  dim3(GG / 4), dim3(256), 0, stream, x, w1, w2, seg, out);
}

// Round 7
// 76.989 us; speedup vs baseline: 2.5295x; 2.5295x over previous
//
#include <hip/hip_runtime.h>
#include <math.h>

#define GG 2000   // num_graphs (reference constant)

typedef short bf16x8 __attribute__((ext_vector_type(8)));
typedef float f32x4  __attribute__((ext_vector_type(4)));

__device__ __forceinline__ unsigned short f2b(float f) {
    unsigned int u = __float_as_uint(f);
    u += 0x7FFFu + ((u >> 16) & 1u);          // round-to-nearest-even
    return (unsigned short)(u >> 16);
}

// seg[g] = first node index with batch[node] >= g, g in [0, GG]
__global__ void lbound_kernel(const int* __restrict__ batch, int* __restrict__ seg, int n) {
    int g = blockIdx.x * blockDim.x + threadIdx.x;
    if (g > GG) return;
    int lo = 0, hi = n;
    while (lo < hi) { int mid = (lo + hi) >> 1; if (batch[mid] < g) lo = mid + 1; else hi = mid; }
    seg[g] = lo;
}

// Block-per-graph (grid-stride), cooperative coalesced chunk staging (64 nodes,
// double-buffered, T14 issue-early/write-late), then ALL per-wave: wave w owns
// chunk rows w*16..w*16+15 -> GEMM1 (MFMA), tanh->hb, GEMM2, in-wave online
// softmax (shfl only), fp32 PV (global x, L1/L2-hot). One merge per graph.
__global__ __launch_bounds__(256, 2) void fused_kernel(
    const float* __restrict__ x, const float* __restrict__ w1,
    const float* __restrict__ w2, const int* __restrict__ seg,
    float* __restrict__ out)
{
    __shared__ __align__(16) unsigned short w1b[16384];   // [128 hid][128 k] bf16, slot^=(row&7)
    __shared__ __align__(16) unsigned short xb[2][8192];  // dbuf [64 node][128 k] bf16, swizzled
    __shared__ __align__(16) unsigned short hb[4][2048];  // per-wave [16 m][128 n]; aliased as oa-merge [8 o][128 f] f32
    __shared__ __align__(16) float pb[4][128];            // per-wave P [16 j][8 o]
    __shared__ float mlb[4][2][8];                        // per-wave (m, l) per head

    const int t = threadIdx.x;
    const int lane = t & 63;
    const int w = t >> 6;
    const int l15 = lane & 15;
    const int lg = lane >> 4;
    const int srow = t >> 5;      // staging: rows srow, srow+8, ..., srow+56
    const int sq = t & 31;        // staging: float4 column

    // ---- stage w1 -> bf16 LDS once per block ----
#pragma unroll
    for (int i = 0; i < 16; ++i) {
        int f4 = i * 256 + t;                  // 4096 float4
        int row = f4 >> 5, q = f4 & 31;
        float4 v = ((const float4*)w1)[f4];
        ushort4 p;
        p.x = f2b(v.x); p.y = f2b(v.y); p.z = f2b(v.z); p.w = f2b(v.w);
        int slot = (q >> 1) ^ (row & 7);
        *(ushort4*)((char*)w1b + row * 256 + slot * 16 + (q & 1) * 8) = p;
    }
    // ---- w2 b-frags in regs: lane -> col o=l15 (rows 8..15 zero) ----
    bf16x8 w2f[4];
    {
        const int o = l15;
#pragma unroll
        for (int ks = 0; ks < 4; ++ks) {
            float tmp[8];
            if (o < 8) {
                float4 u0 = ((const float4*)w2)[o * 32 + ks * 8 + lg * 2];
                float4 u1 = ((const float4*)w2)[o * 32 + ks * 8 + lg * 2 + 1];
                tmp[0]=u0.x; tmp[1]=u0.y; tmp[2]=u0.z; tmp[3]=u0.w;
                tmp[4]=u1.x; tmp[5]=u1.y; tmp[6]=u1.z; tmp[7]=u1.w;
            } else {
#pragma unroll
                for (int i = 0; i < 8; ++i) tmp[i] = 0.f;
            }
            bf16x8 r;
#pragma unroll
            for (int i = 0; i < 8; ++i) r[i] = (short)f2b(tmp[i]);
            w2f[ks] = r;
        }
    }
    __syncthreads();   // w1b staged
    // ---- hoist w1 B-frags for nt=0..3 into registers ----
    bf16x8 bfreg[4][4];
#pragma unroll
    for (int ks = 0; ks < 4; ++ks)
#pragma unroll
        for (int nt = 0; nt < 4; ++nt) {
            int brow = nt * 16 + l15;
            int slot = (ks * 4 + lg) ^ (brow & 7);
            bfreg[ks][nt] = *(bf16x8*)((char*)w1b + brow * 256 + slot * 16);
        }

    char*  myhb = (char*)hb + w * 4096;
    float* mypb = pb[w];

    for (int g = blockIdx.x; g < GG; g += gridDim.x) {
        const int s = seg[g];
        const int e = seg[g + 1];
        float* og = out + (size_t)g * 1024;
        if (e <= s) {           // empty graph (block-uniform branch)
            og[t] = 0.f; og[t + 256] = 0.f; og[t + 512] = 0.f; og[t + 768] = 0.f;
            continue;
        }

        // ---- preload + write chunk 0 (prev graph's compute all ended before its merge barrier) ----
        float4 pre[8];
#pragma unroll
        for (int i = 0; i < 8; ++i) {
            int node = s + i * 8 + srow;
            if (node >= e) node = e - 1;
            pre[i] = ((const float4*)x)[(size_t)node * 32 + sq];
        }
#pragma unroll
        for (int i = 0; i < 8; ++i) {
            int row = i * 8 + srow;
            ushort4 p;
            p.x = f2b(pre[i].x); p.y = f2b(pre[i].y); p.z = f2b(pre[i].z); p.w = f2b(pre[i].w);
            int slot = (sq >> 1) ^ (row & 7);
            *(ushort4*)((char*)xb + row * 256 + slot * 16 + (sq & 1) * 8) = p;
        }
        __syncthreads();        // chunk 0 ready (also orders prev merge-reads before tanh below)

        float oa[8][2];
#pragma unroll
        for (int o = 0; o < 8; ++o) { oa[o][0] = 0.f; oa[o][1] = 0.f; }
        float mo = -INFINITY, ls = 0.f;

        const int nc = (e - s + 63) >> 6;
        for (int c = 0; c < nc; ++c) {
            const int nb = s + c * 64;
            // T14: issue next chunk's loads before compute
            if (c + 1 < nc) {
#pragma unroll
                for (int i = 0; i < 8; ++i) {
                    int node = nb + 64 + i * 8 + srow;
                    if (node >= e) node = e - 1;
                    pre[i] = ((const float4*)x)[(size_t)node * 32 + sq];
                }
            }
            // ---- per-wave compute on rows nb+w*16 .. nb+w*16+15 ----
            if (nb + w * 16 < e) {
                const char* xbuf = (const char*)xb + (c & 1) * 16384;
                f32x4 acc1[8];
#pragma unroll
                for (int nt = 0; nt < 8; ++nt)
#pragma unroll
                    for (int r = 0; r < 4; ++r) acc1[nt][r] = 0.f;
#pragma unroll
                for (int ks = 0; ks < 4; ++ks) {
                    int arow = w * 16 + l15;
                    int aslot = (ks * 4 + lg) ^ (arow & 7);
                    bf16x8 af = *(const bf16x8*)(xbuf + arow * 256 + aslot * 16);
#pragma unroll
                    for (int nt = 0; nt < 4; ++nt)
                        acc1[nt] = __builtin_amdgcn_mfma_f32_16x16x32_bf16(af, bfreg[ks][nt], acc1[nt], 0, 0, 0);
#pragma unroll
                    for (int nt = 4; nt < 8; ++nt) {
                        int brow = nt * 16 + l15;
                        int bslot = (ks * 4 + lg) ^ (brow & 7);
                        bf16x8 bfr = *(bf16x8*)((char*)w1b + brow * 256 + bslot * 16);
                        acc1[nt] = __builtin_amdgcn_mfma_f32_16x16x32_bf16(af, bfr, acc1[nt], 0, 0, 0);
                    }
                }
                // tanh -> myhb (wave-private, in-wave LDS ordering)
#pragma unroll
                for (int nt = 0; nt < 8; ++nt)
#pragma unroll
                    for (int r = 0; r < 4; ++r) {
                        float aa = acc1[nt][r];
                        float eo = __expf(-2.f * fabsf(aa));
                        float th = copysignf((1.f - eo) * __builtin_amdgcn_rcpf(1.f + eo), aa);
                        int m = lg * 4 + r;
                        int n = nt * 16 + l15;
                        int slot = (n >> 3) ^ (m & 7);
                        *(unsigned short*)(myhb + m * 256 + slot * 16 + (n & 7) * 2) = f2b(th);
                    }
                // GEMM2: scores for the wave's 16 rows x 8 heads
                f32x4 acc2;
#pragma unroll
                for (int r = 0; r < 4; ++r) acc2[r] = 0.f;
#pragma unroll
                for (int ks = 0; ks < 4; ++ks) {
                    int slot = (ks * 4 + lg) ^ (l15 & 7);
                    bf16x8 hf = *(bf16x8*)(myhb + l15 * 256 + slot * 16);
                    acc2 = __builtin_amdgcn_mfma_f32_16x16x32_bf16(hf, w2f[ks], acc2, 0, 0, 0);
                }
                // in-wave online softmax: head o = l15, rows lg*4+r
                float sreg[4];
#pragma unroll
                for (int r = 0; r < 4; ++r) {
                    int node = nb + w * 16 + lg * 4 + r;
                    sreg[r] = (l15 < 8 && node < e) ? acc2[r] : -INFINITY;
                }
                float pm = fmaxf(fmaxf(sreg[0], sreg[1]), fmaxf(sreg[2], sreg[3]));
                pm = fmaxf(pm, __shfl_xor(pm, 16));
                pm = fmaxf(pm, __shfl_xor(pm, 32));
                float mn = fmaxf(mo, pm);
                float fac = __expf(mo - mn);      // NaN on l15>=8 lanes, never consumed
                mo = mn;
                float psum = 0.f;
#pragma unroll
                for (int r = 0; r < 4; ++r) {
                    float p = __expf(sreg[r] - mn);
                    psum += p;
                    if (l15 < 8) mypb[(lg * 4 + r) * 8 + l15] = p;
                }
                psum += __shfl_xor(psum, 16);
                psum += __shfl_xor(psum, 32);
                ls = ls * fac + psum;
                // rescale + PV (fp32 x from global; rows L1/L2-hot from staging)
                float fac8[8];
#pragma unroll
                for (int o = 0; o < 8; ++o) fac8[o] = __shfl(fac, o);
#pragma unroll
                for (int o = 0; o < 8; ++o) { oa[o][0] *= fac8[o]; oa[o][1] *= fac8[o]; }
#pragma unroll
                for (int j = 0; j < 16; ++j) {
                    int node = nb + w * 16 + j;
                    if (node >= e) node = e - 1;          // its p row is 0
                    float xv0 = x[(size_t)node * 128 + lane];
                    float xv1 = x[(size_t)node * 128 + 64 + lane];
                    float4 p0 = ((const float4*)mypb)[j * 2];
                    float4 p1 = ((const float4*)mypb)[j * 2 + 1];
                    oa[0][0] = fmaf(p0.x, xv0, oa[0][0]); oa[0][1] = fmaf(p0.x, xv1, oa[0][1]);
                    oa[1][0] = fmaf(p0.y, xv0, oa[1][0]); oa[1][1] = fmaf(p0.y, xv1, oa[1][1]);
                    oa[2][0] = fmaf(p0.z, xv0, oa[2][0]); oa[2][1] = fmaf(p0.z, xv1, oa[2][1]);
                    oa[3][0] = fmaf(p0.w, xv0, oa[3][0]); oa[3][1] = fmaf(p0.w, xv1, oa[3][1]);
                    oa[4][0] = fmaf(p1.x, xv0, oa[4][0]); oa[4][1] = fmaf(p1.x, xv1, oa[4][1]);
                    oa[5][0] = fmaf(p1.y, xv0, oa[5][0]); oa[5][1] = fmaf(p1.y, xv1, oa[5][1]);
                    oa[6][0] = fmaf(p1.z, xv0, oa[6][0]); oa[6][1] = fmaf(p1.z, xv1, oa[6][1]);
                    oa[7][0] = fmaf(p1.w, xv0, oa[7][0]); oa[7][1] = fmaf(p1.w, xv1, oa[7][1]);
                }
            }
            // T14 write-late: convert + ds_write next chunk, then one barrier
            if (c + 1 < nc) {
#pragma unroll
                for (int i = 0; i < 8; ++i) {
                    int row = i * 8 + srow;
                    ushort4 p;
                    p.x = f2b(pre[i].x); p.y = f2b(pre[i].y); p.z = f2b(pre[i].z); p.w = f2b(pre[i].w);
                    int slot = (sq >> 1) ^ (row & 7);
                    *(ushort4*)((char*)xb + ((c + 1) & 1) * 16384 + row * 256 + slot * 16 + (sq & 1) * 8) = p;
                }
                __syncthreads();
            }
        }
        // ---- merge: per-wave (m, l, oa) -> block result ----
        if (lg == 0 && l15 < 8) { mlb[w][0][l15] = mo; mlb[w][1][l15] = ls; }
        float* oab = (float*)hb + w * 1024;   // [8 o][128 f], hb no longer needed
#pragma unroll
        for (int o = 0; o < 8; ++o) {
            oab[o * 128 + lane] = oa[o][0];
            oab[o * 128 + 64 + lane] = oa[o][1];
        }
        __syncthreads();
        {
            const int f = t & 127, ob = t >> 7;
            const float* hbf = (const float*)hb;
#pragma unroll
            for (int i = 0; i < 4; ++i) {
                int o = ob * 4 + i;
                float m0 = mlb[0][0][o], m1 = mlb[1][0][o], m2 = mlb[2][0][o], m3 = mlb[3][0][o];
                float ms = fmaxf(fmaxf(m0, m1), fmaxf(m2, m3));   // finite: wave 0 always valid
                float e0 = __expf(m0 - ms), e1 = __expf(m1 - ms);
                float e2 = __expf(m2 - ms), e3 = __expf(m3 - ms);
                float den = mlb[0][1][o] * e0 + mlb[1][1][o] * e1 + mlb[2][1][o] * e2 + mlb[3][1][o] * e3;
                float num = hbf[o * 128 + f] * e0 + hbf[1024 + o * 128 + f] * e1
                          + hbf[2048 + o * 128 + f] * e2 + hbf[3072 + o * 128 + f] * e3;
                og[o * 128 + f] = num / den;
            }
        }
        // next graph's post-stage barrier orders these merge reads before hb reuse
    }
}

extern "C" void kernel_launch(void* const* d_in, const int* in_sizes, int n_in,
                              void* d_out, int out_size, void* d_ws, size_t ws_size,
                              hipStream_t stream)
{
    const float* x     = (const float*)d_in[0];
    const int*   batch = (const int*)d_in[1];
    const float* w1    = (const float*)d_in[2];
    const float* w2    = (const float*)d_in[3];
    const int n_nodes  = in_sizes[1];
    float* out = (float*)d_out;

    int* seg = (int*)d_ws;   // GG+1 ints

    hipLaunchKernelGGL(lbound_kernel, dim3((GG + 256) / 256), dim3(256), 0, stream, batch, seg, n_nodes);
    hipLaunchKernelGGL(fused_kernel,  dim3(512), dim3(256), 0, stream, x, w1, w2, seg, out);
}

// Round 8
// 65.878 us; speedup vs baseline: 2.9561x; 1.1687x over previous
//
#include <hip/hip_runtime.h>
#include <math.h>

#define GG 2000   // num_graphs (reference constant)

typedef short bf16x8 __attribute__((ext_vector_type(8)));
typedef float f32x4  __attribute__((ext_vector_type(4)));

__device__ __forceinline__ unsigned short f2b(float f) {
    unsigned int u = __float_as_uint(f);
    u += 0x7FFFu + ((u >> 16) & 1u);          // round-to-nearest-even
    return (unsigned short)(u >> 16);
}

// seg[g] = first node index with batch[node] >= g, g in [0, GG]
__global__ void lbound_kernel(const int* __restrict__ batch, int* __restrict__ seg, int n) {
    int g = blockIdx.x * blockDim.x + threadIdx.x;
    if (g > GG) return;
    int lo = 0, hi = n;
    while (lo < hi) { int mid = (lo + hi) >> 1; if (batch[mid] < g) lo = mid + 1; else hi = mid; }
    seg[g] = lo;
}

// ---------------- Phase A: scores = tanh(x@w1^T)@w2^T, flat 64-node tiles ----------------
// Grid-stride 768 blocks (3/CU), 4 waves; wave w owns tile rows w*16..w*16+15.
// Stage x tile coalesced -> bf16 LDS (swizzled); GEMM1 vs LDS w1b; tanh written
// over the wave's OWN xb rows (data-dep safe); GEMM2 vs reg w2 frags; store scores.
__global__ __launch_bounds__(256, 3) void score_kernel(
    const float* __restrict__ x, const float* __restrict__ w1,
    const float* __restrict__ w2, float* __restrict__ scores,
    int n_nodes, int ntile)
{
    __shared__ __align__(16) unsigned short w1b[16384];  // [128 hid][128 k] bf16, slot^=(row&7)
    __shared__ __align__(16) unsigned short xb[8192];    // [64 n][128 k] bf16; h aliases per-wave rows

    const int t = threadIdx.x;
    const int lane = t & 63;
    const int w = t >> 6;
    const int l15 = lane & 15;
    const int lg = lane >> 4;
    const int srow = t >> 5;      // staging row within octet
    const int sq = t & 31;        // staging float4 column

    // ---- stage w1 -> bf16 LDS once per block ----
#pragma unroll
    for (int i = 0; i < 16; ++i) {
        int f4 = i * 256 + t;                  // 4096 float4
        int row = f4 >> 5, q = f4 & 31;
        float4 v = ((const float4*)w1)[f4];
        ushort4 p;
        p.x = f2b(v.x); p.y = f2b(v.y); p.z = f2b(v.z); p.w = f2b(v.w);
        int slot = (q >> 1) ^ (row & 7);
        *(ushort4*)((char*)w1b + row * 256 + slot * 16 + (q & 1) * 8) = p;
    }
    // ---- w2 b-frags in regs: lane -> col o=l15 (rows 8..15 zero) ----
    bf16x8 w2f[4];
    {
        const int o = l15;
#pragma unroll
        for (int ks = 0; ks < 4; ++ks) {
            float tmp[8];
            if (o < 8) {
                float4 u0 = ((const float4*)w2)[o * 32 + ks * 8 + lg * 2];
                float4 u1 = ((const float4*)w2)[o * 32 + ks * 8 + lg * 2 + 1];
                tmp[0]=u0.x; tmp[1]=u0.y; tmp[2]=u0.z; tmp[3]=u0.w;
                tmp[4]=u1.x; tmp[5]=u1.y; tmp[6]=u1.z; tmp[7]=u1.w;
            } else {
#pragma unroll
                for (int i = 0; i < 8; ++i) tmp[i] = 0.f;
            }
            bf16x8 r;
#pragma unroll
            for (int i = 0; i < 8; ++i) r[i] = (short)f2b(tmp[i]);
            w2f[ks] = r;
        }
    }

    char* myhb = (char*)xb + w * 4096;   // wave-private 16 rows (x then h)

    for (int tile = blockIdx.x; tile < ntile; tile += gridDim.x) {
        const int base = tile * 64;
        __syncthreads();                 // prev tile fully consumed (and w1b on iter 0)
        // ---- stage x tile: 64 nodes x 128 k, coalesced ----
#pragma unroll
        for (int i = 0; i < 8; ++i) {
            int row = i * 8 + srow;
            int node = base + row; if (node >= n_nodes) node = n_nodes - 1;
            float4 v = ((const float4*)x)[(size_t)node * 32 + sq];
            ushort4 p;
            p.x = f2b(v.x); p.y = f2b(v.y); p.z = f2b(v.z); p.w = f2b(v.w);
            int slot = (sq >> 1) ^ (row & 7);
            *(ushort4*)((char*)xb + row * 256 + slot * 16 + (sq & 1) * 8) = p;
        }
        __syncthreads();
        // ---- GEMM1: wave rows w*16..+15 x 128 hidden ----
        f32x4 acc1[8];
#pragma unroll
        for (int nt = 0; nt < 8; ++nt)
#pragma unroll
            for (int r = 0; r < 4; ++r) acc1[nt][r] = 0.f;
#pragma unroll
        for (int ks = 0; ks < 4; ++ks) {
            int arow = w * 16 + l15;
            int aslot = (ks * 4 + lg) ^ (arow & 7);
            bf16x8 af = *(const bf16x8*)((char*)xb + arow * 256 + aslot * 16);
#pragma unroll
            for (int nt = 0; nt < 8; ++nt) {
                int brow = nt * 16 + l15;
                int bslot = (ks * 4 + lg) ^ (brow & 7);
                bf16x8 bfr = *(bf16x8*)((char*)w1b + brow * 256 + bslot * 16);
                acc1[nt] = __builtin_amdgcn_mfma_f32_16x16x32_bf16(af, bfr, acc1[nt], 0, 0, 0);
            }
        }
        // ---- tanh -> own rows (aliases xb; write value data-depends on all reads) ----
#pragma unroll
        for (int nt = 0; nt < 8; ++nt)
#pragma unroll
            for (int r = 0; r < 4; ++r) {
                float aa = acc1[nt][r];
                float eo = __expf(-2.f * fabsf(aa));
                float th = copysignf((1.f - eo) * __builtin_amdgcn_rcpf(1.f + eo), aa);
                int m = lg * 4 + r;
                int n = nt * 16 + l15;
                int slot = (n >> 3) ^ (m & 7);
                *(unsigned short*)(myhb + m * 256 + slot * 16 + (n & 7) * 2) = f2b(th);
            }
        // ---- GEMM2: scores for the wave's 16 rows x 8 heads (cols 8..15 pad) ----
        f32x4 acc2;
#pragma unroll
        for (int r = 0; r < 4; ++r) acc2[r] = 0.f;
#pragma unroll
        for (int ks = 0; ks < 4; ++ks) {
            int slot = (ks * 4 + lg) ^ (l15 & 7);
            bf16x8 hf = *(bf16x8*)(myhb + l15 * 256 + slot * 16);
            acc2 = __builtin_amdgcn_mfma_f32_16x16x32_bf16(hf, w2f[ks], acc2, 0, 0, 0);
        }
        if (l15 < 8) {
#pragma unroll
            for (int r = 0; r < 4; ++r) {
                int node = base + w * 16 + lg * 4 + r;
                if (node < n_nodes) scores[node * 8 + l15] = acc2[r];
            }
        }
    }
}

// ---------------- Phase B: per-graph max and 1/sum(exp) ----------------
__global__ __launch_bounds__(256) void segstat_kernel(
    const float* __restrict__ scores, const int* __restrict__ seg,
    float* __restrict__ gmax, float* __restrict__ ginv)
{
    __shared__ float red[256];
    __shared__ float gmx[8];
    const int g = blockIdx.x, t = threadIdx.x;
    const int s = seg[g];
    const int e = seg[g + 1];
    const int o = t & 7, j = t >> 3;

    float m = -INFINITY;
    for (int n = s + j; n < e; n += 32) m = fmaxf(m, scores[n * 8 + o]);
    red[t] = m;
    __syncthreads();
    for (int st = 128; st >= 8; st >>= 1) {
        if (t < st) red[t] = fmaxf(red[t], red[t + st]);
        __syncthreads();
    }
    if (t < 8) gmx[t] = red[t];
    __syncthreads();
    const float gm = gmx[o];
    float sacc = 0.f;
    for (int n = s + j; n < e; n += 32) sacc += __expf(scores[n * 8 + o] - gm);
    __syncthreads();
    red[t] = sacc;
    __syncthreads();
    for (int st = 128; st >= 8; st >>= 1) {
        if (t < st) red[t] += red[t + st];
        __syncthreads();
    }
    if (t < 8) {
        gmax[g * 8 + t] = gmx[t];
        ginv[g * 8 + t] = 1.f / red[t];   // inf for empty graph: never consumed
    }
}

// ---------------- Phase C: out[g][o][f] = sum_n attn[n][o] * x[n][f] ----------------
__global__ __launch_bounds__(256) void out_kernel(
    const float* __restrict__ x, const float* __restrict__ scores,
    const int* __restrict__ seg, const float* __restrict__ gmax,
    const float* __restrict__ ginv, float* __restrict__ out)
{
    __shared__ __align__(16) float xsl[16 * 128];
    __shared__ __align__(16) float atl[16 * 8];
    const int g = blockIdx.x, t = threadIdx.x;
    const int s = seg[g];
    const int e = seg[g + 1];
    const int f = t & 127, ob = t >> 7;    // thread covers o in {4*ob..4*ob+3} at feature f
    float a0 = 0.f, a1 = 0.f, a2 = 0.f, a3 = 0.f;

    for (int c = s; c < e; c += 16) {
        const int cnt = min(16, e - c);
        __syncthreads();   // protects prev-iter reads
#pragma unroll
        for (int i = 0; i < 2; ++i) {
            int f4 = i * 256 + t;
            int row = f4 >> 5, col4 = f4 & 31;
            if (row < cnt)
                ((float4*)xsl)[row * 32 + col4] = ((const float4*)x)[(size_t)(c + row) * 32 + col4];
        }
        if (t < 128) {
            int j = t >> 3, o = t & 7;
            if (j < cnt)
                atl[j * 8 + o] = __expf(scores[(c + j) * 8 + o] - gmax[g * 8 + o]) * ginv[g * 8 + o];
        }
        __syncthreads();
        for (int j = 0; j < cnt; ++j) {
            float xv = xsl[j * 128 + f];
            float4 a4 = ((const float4*)atl)[j * 2 + ob];
            a0 += a4.x * xv; a1 += a4.y * xv; a2 += a4.z * xv; a3 += a4.w * xv;
        }
    }
    const int gb = g * 1024 + ob * 512 + f;
    out[gb]       = a0;     // empty graph: accs are 0 = segment_sum identity
    out[gb + 128] = a1;
    out[gb + 256] = a2;
    out[gb + 384] = a3;
}

extern "C" void kernel_launch(void* const* d_in, const int* in_sizes, int n_in,
                              void* d_out, int out_size, void* d_ws, size_t ws_size,
                              hipStream_t stream)
{
    const float* x     = (const float*)d_in[0];
    const int*   batch = (const int*)d_in[1];
    const float* w1    = (const float*)d_in[2];
    const float* w2    = (const float*)d_in[3];
    const int n_nodes  = in_sizes[1];
    float* out = (float*)d_out;

    float* scores = (float*)d_ws;                          // n*8 floats
    float* gmax   = scores + (size_t)n_nodes * 8;          // GG*8
    float* ginv   = gmax + (size_t)GG * 8;                 // GG*8
    int*   seg    = (int*)(ginv + (size_t)GG * 8);         // GG+1 ints

    const int ntile = (n_nodes + 63) / 64;
    hipLaunchKernelGGL(lbound_kernel,  dim3((GG + 256) / 256), dim3(256), 0, stream, batch, seg, n_nodes);
    hipLaunchKernelGGL(score_kernel,   dim3(768), dim3(256), 0, stream, x, w1, w2, scores, n_nodes, ntile);
    hipLaunchKernelGGL(segstat_kernel, dim3(GG),  dim3(256), 0, stream, scores, seg, gmax, ginv);
    hipLaunchKernelGGL(out_kernel,     dim3(GG),  dim3(256), 0, stream, x, scores, seg, gmax, ginv, out);
}